// Round 5
// baseline (254.294 us; speedup 1.0000x reference)
//
#include <hip/hip_runtime.h>

// Conv2d 3x3 pad1 stride1, x[1,256,224,224] f32, w[256,256,3,3] f32 -> out[256,224,224] f32
// Implicit GEMM: M=256 (co), N=50176 (h*224+w), K=2304 (tap-major: k = (dh*3+dw)*256 + ci)
// R5: back to R3's 128x128 BK=32 dbuf core (proven 106us), + split-K=2 (grid 1568 blocks,
//     ~5 resident/CU by LDS) with deterministic 2-way f32 atomic adds; out-zero fused
//     into prologue. Density per wave preserved (16 MFMA/iter), occupancy ~2x.

#define H 224
#define W 224
#define NPOS (H*W)          // 50176
#define CI 256
#define CO 256
#define KDIM 2304
#define HP 226              // padded
#define XP_ELEMS (HP*HP*CI) // 13,075,456 shorts
#define AP_ELEMS (CO*KDIM)  // 589,824 shorts

#define ZERO_BLOCKS 12544   // (256*224*224)/4 float4 / 256 threads
#define W_BLOCKS    (AP_ELEMS / 256)   // 2304
#define BORDER_BLOCKS 900

typedef __bf16 bf16x8 __attribute__((ext_vector_type(8)));
typedef float f32x4 __attribute__((ext_vector_type(4)));

__device__ __forceinline__ unsigned short f2bf(float f) {
    unsigned int u = __float_as_uint(f);
    u += 0x7fff + ((u >> 16) & 1);   // round-to-nearest-even
    return (unsigned short)(u >> 16);
}

__device__ __forceinline__ void load_lds16(const unsigned short* g, unsigned short* l) {
    __builtin_amdgcn_global_load_lds(
        (const __attribute__((address_space(1))) void*)g,
        (__attribute__((address_space(3))) void*)l,
        16, 0, 0);
}

// ---- fused prologue:
//   blocks [0, ZERO_BLOCKS)                 : zero d_out (float4)
//   blocks [ZERO_BLOCKS, +W_BLOCKS)         : weight f32 [co][ci][3][3] -> bf16 A'[co][tap*256+ci]
//   blocks [.., +BORDER_BLOCKS)             : zero 1-px border of Xp[226][226][256]
__global__ void prologue_kernel(const float* __restrict__ w, unsigned short* __restrict__ ap,
                                unsigned short* __restrict__ xp, float* __restrict__ out) {
    if (blockIdx.x < ZERO_BLOCKS) {
        f32x4* o4 = (f32x4*)out;
        o4[blockIdx.x * 256 + threadIdx.x] = (f32x4){0.f, 0.f, 0.f, 0.f};
    } else if (blockIdx.x < ZERO_BLOCKS + W_BLOCKS) {
        int o = (blockIdx.x - ZERO_BLOCKS) * 256 + threadIdx.x;  // co*2304 + tap*256 + ci
        int co = o / KDIM;
        int rem = o - co * KDIM;
        int tap = rem >> 8;
        int ci = rem & 255;
        ap[o] = f2bf(w[(co * CI + ci) * 9 + tap]);
    } else {
        int idx = (blockIdx.x - ZERO_BLOCKS - W_BLOCKS) * 256 + threadIdx.x;  // 230400 total
        int hp, wp, ci;
        if (idx < 2 * HP * CI) {                 // rows 0 and 225
            int r = idx / (HP * CI);
            int rem = idx - r * (HP * CI);
            hp = r * (HP - 1);
            wp = rem / CI;
            ci = rem & (CI - 1);
        } else {
            int i2 = idx - 2 * HP * CI;          // cols 0 and 225, h=1..224
            int side = i2 / (H * CI);
            int rem = i2 - side * (H * CI);
            hp = 1 + rem / CI;
            wp = side * (HP - 1);
            ci = rem & (CI - 1);
        }
        xp[(hp * HP + wp) * CI + ci] = 0;
    }
}

// ---- input: f32 [ci][224][224] -> bf16 padded NHWC Xp[226][226][256] interior ----
// LDS-tiled transpose: 64 ci x 64 p per block; both global phases coalesced.
__global__ void xtrans_kernel(const float* __restrict__ x, unsigned short* __restrict__ xp) {
    __shared__ unsigned short tile[64][66];
    const unsigned int pBase = blockIdx.x * 64;
    const unsigned int ciBase = blockIdx.y * 64;
    const unsigned int t = threadIdx.x;
    {
        const unsigned int p_l = t & 63;
        const unsigned int c0 = t >> 6;          // 0..3
#pragma unroll
        for (int i = 0; i < 16; ++i) {
            const unsigned int ci_l = c0 + i * 4;
            tile[ci_l][p_l] = f2bf(x[(ciBase + ci_l) * NPOS + pBase + p_l]);
        }
    }
    __syncthreads();
    {
        const unsigned int ci_l = t & 63;
        const unsigned int p0 = t >> 6;          // 0..3
#pragma unroll
        for (int i = 0; i < 16; ++i) {
            const unsigned int p_l = p0 + i * 4;
            const unsigned int p = pBase + p_l;
            const unsigned int hi = p / W;
            const unsigned int wi = p - hi * W;
            xp[((hi + 1) * HP + (wi + 1)) * CI + ciBase + ci_l] = tile[ci_l][p_l];
        }
    }
}

// ---- implicit GEMM, split-K=2: 128x128 tile, BK=32, dbuf LDS, one barrier/iter ----
// blockIdx.z = Kh selects K-chunks [Kh*36, Kh*36+36). Epilogue: atomic f32 add
// (exactly 2 contributions per element -> commutative -> deterministic).
// Swizzle (4 chunks of 8 shorts per 32-short row):
//   store: lane l -> row {j*64 + wave*16 + (l>>2)}, slot l&3, source chunk (l&3)^((l>>2)&3)
//   read : chunk quad of row r lives at slot quad^(r&3); r&3 == ln15&3
__global__ __launch_bounds__(256) void gemm_conv_kernel(
    const unsigned short* __restrict__ Ap,   // [256][2304] bf16
    const unsigned short* __restrict__ Xp,   // [226][226][256] bf16
    float* __restrict__ out)                 // [256][50176]
{
    __shared__ unsigned short Als[2][4096];
    __shared__ unsigned short Bls[2][4096];

    const int tid = threadIdx.x;
    const int Nb = blockIdx.x;               // 0..391
    const int Mb = blockIdx.y;               // 0..1
    const int Kh = blockIdx.z;               // 0..1
    const int wave = tid >> 6;
    const int lane = tid & 63;
    const int ln15 = lane & 15;
    const int quad = lane >> 4;
    const int wm = wave >> 1;
    const int wn = wave & 1;
    const int sw = ln15 & 3;

    // ---- staging source pointers ----
    const int l2 = lane >> 2;                // 0..15
    const int c4 = (lane & 3) ^ (l2 & 3);    // swizzled source chunk

    const unsigned short* a_src[2];
    const unsigned short* b_src[2];
#pragma unroll
    for (int j = 0; j < 2; ++j) {
        const int row = j * 64 + wave * 16 + l2;           // 0..127
        a_src[j] = Ap + (Mb * 128 + row) * KDIM + c4 * 8;  // + kc*32
        unsigned int p = Nb * 128 + row;
        unsigned int hi = p / W, wi = p - hi * W;
        b_src[j] = Xp + (hi * HP + wi) * CI + c4 * 8;      // + tap/ci offset
    }

    f32x4 acc[4][4];
#pragma unroll
    for (int mi = 0; mi < 4; ++mi)
#pragma unroll
        for (int ni = 0; ni < 4; ++ni)
            acc[mi][ni] = (f32x4){0.f, 0.f, 0.f, 0.f};

    // stage tile kc into buffer buf (wave-uniform LDS base; lane*16B implicit)
    auto stage = [&](int kc, int buf) {
        const int tap = kc >> 3;             // 0..8
        const int dh = tap / 3, dw = tap - dh * 3;
        const int boff = (dh * HP + dw) * CI + (kc & 7) * 32;
        const int aoff = kc * 32;
#pragma unroll
        for (int j = 0; j < 2; ++j) {
            load_lds16(a_src[j] + aoff, &Als[buf][j * 2048 + wave * 512]);
            load_lds16(b_src[j] + boff, &Bls[buf][j * 2048 + wave * 512]);
        }
    };

    const int kc0 = Kh * 36;
    stage(kc0, 0);
    __syncthreads();                         // drain vmcnt: buffer 0 ready

    for (int i = 0; i < 36; ++i) {
        const int cur = i & 1;
        if (i < 35) stage(kc0 + i + 1, cur ^ 1); // async into the OTHER buffer

        bf16x8 af[4], bfr[4];
#pragma unroll
        for (int mi = 0; mi < 4; ++mi)
            af[mi] = *(const bf16x8*)&Als[cur][(wm * 64 + mi * 16 + ln15) * 32 +
                                              ((quad ^ sw) * 8)];
#pragma unroll
        for (int ni = 0; ni < 4; ++ni)
            bfr[ni] = *(const bf16x8*)&Bls[cur][(wn * 64 + ni * 16 + ln15) * 32 +
                                               ((quad ^ sw) * 8)];
#pragma unroll
        for (int mi = 0; mi < 4; ++mi)
#pragma unroll
            for (int ni = 0; ni < 4; ++ni)
                acc[mi][ni] = __builtin_amdgcn_mfma_f32_16x16x32_bf16(
                    af[mi], bfr[ni], acc[mi][ni], 0, 0, 0);

        __syncthreads();                     // joins: reads of cur done, next buffer landed
    }

    // epilogue: C/D layout col = lane&15 (n=p), row = quad*4 + reg (m=co)
    const int pcol = Nb * 128 + wn * 64 + ln15;
    const int corow = Mb * 128 + wm * 64 + quad * 4;
#pragma unroll
    for (int mi = 0; mi < 4; ++mi)
#pragma unroll
        for (int ni = 0; ni < 4; ++ni)
#pragma unroll
            for (int r = 0; r < 4; ++r)
                unsafeAtomicAdd(&out[(corow + mi * 16 + r) * NPOS + pcol + ni * 16],
                                acc[mi][ni][r]);
}

extern "C" void kernel_launch(void* const* d_in, const int* in_sizes, int n_in,
                              void* d_out, int out_size, void* d_ws, size_t ws_size,
                              hipStream_t stream) {
    const float* x = (const float*)d_in[0];       // [1,256,224,224]
    const float* w = (const float*)d_in[1];       // [256,256,3,3]
    float* out = (float*)d_out;                   // [256,224,224]

    unsigned short* xp = (unsigned short*)d_ws;        // 13,075,456 shorts
    unsigned short* ap = xp + XP_ELEMS;                // 589,824 shorts

    prologue_kernel<<<ZERO_BLOCKS + W_BLOCKS + BORDER_BLOCKS, 256, 0, stream>>>(w, ap, xp, out);
    xtrans_kernel<<<dim3(NPOS / 64, CI / 64), 256, 0, stream>>>(x, xp);
    gemm_conv_kernel<<<dim3(NPOS / 128, CO / 128, 2), 256, 0, stream>>>(ap, xp, out);
}

// Round 6
// 196.317 us; speedup vs baseline: 1.2953x; 1.2953x over previous
//
#include <hip/hip_runtime.h>

// Conv2d 3x3 pad1 stride1, x[1,256,224,224] f32, w[256,256,3,3] f32 -> out[256,224,224] f32
// Implicit GEMM: M=256 (co), N=50176 (h*224+w), K=2304 (tap-major: k = (dh*3+dw)*256 + ci)
// R6: LDS-ratio attack. Block 128x128 (grid 784), but 2 waves/block (128 thr), each wave
//     owns 128(M)x64(N): 12 ds_read_b128 -> 32 MFMA (43.7 FLOP/LDS-byte vs 32 in R3).
//     BK=32 dbuf, one barrier/iter. acc=128 AGPR, __launch_bounds__(128,2).

#define H 224
#define W 224
#define NPOS (H*W)          // 50176
#define CI 256
#define CO 256
#define KDIM 2304
#define HP 226              // padded
#define XP_ELEMS (HP*HP*CI) // 13,075,456 shorts
#define AP_ELEMS (CO*KDIM)  // 589,824 shorts

typedef __bf16 bf16x8 __attribute__((ext_vector_type(8)));
typedef float f32x4 __attribute__((ext_vector_type(4)));

__device__ __forceinline__ unsigned short f2bf(float f) {
    unsigned int u = __float_as_uint(f);
    u += 0x7fff + ((u >> 16) & 1);   // round-to-nearest-even
    return (unsigned short)(u >> 16);
}

__device__ __forceinline__ void load_lds16(const unsigned short* g, unsigned short* l) {
    __builtin_amdgcn_global_load_lds(
        (const __attribute__((address_space(1))) void*)g,
        (__attribute__((address_space(3))) void*)l,
        16, 0, 0);
}

// ---- fused: weight f32 [co][ci][3][3] -> bf16 A'[co][tap*256+ci]  (blocks 0..2303)
//      + zero the 1-px border of Xp [226][226][256]                 (blocks 2304..3203)
__global__ void prologue_kernel(const float* __restrict__ w, unsigned short* __restrict__ ap,
                                unsigned short* __restrict__ xp) {
    if (blockIdx.x < AP_ELEMS / 256) {
        int o = blockIdx.x * 256 + threadIdx.x;  // o = co*2304 + tap*256 + ci
        int co = o / KDIM;
        int rem = o - co * KDIM;
        int tap = rem >> 8;
        int ci = rem & 255;
        ap[o] = f2bf(w[(co * CI + ci) * 9 + tap]);
    } else {
        int idx = (blockIdx.x - AP_ELEMS / 256) * 256 + threadIdx.x;  // 230400 total
        int hp, wp, ci;
        if (idx < 2 * HP * CI) {                 // rows 0 and 225
            int r = idx / (HP * CI);
            int rem = idx - r * (HP * CI);
            hp = r * (HP - 1);
            wp = rem / CI;
            ci = rem & (CI - 1);
        } else {
            int i2 = idx - 2 * HP * CI;          // cols 0 and 225, h=1..224
            int side = i2 / (H * CI);
            int rem = i2 - side * (H * CI);
            hp = 1 + rem / CI;
            wp = side * (HP - 1);
            ci = rem & (CI - 1);
        }
        xp[(hp * HP + wp) * CI + ci] = 0;
    }
}

// ---- input: f32 [ci][224][224] -> bf16 padded NHWC Xp[226][226][256] interior ----
// LDS-tiled transpose: 64 ci x 64 p per block; both global phases coalesced.
__global__ void xtrans_kernel(const float* __restrict__ x, unsigned short* __restrict__ xp) {
    __shared__ unsigned short tile[64][66];
    const unsigned int pBase = blockIdx.x * 64;
    const unsigned int ciBase = blockIdx.y * 64;
    const unsigned int t = threadIdx.x;
    {
        const unsigned int p_l = t & 63;
        const unsigned int c0 = t >> 6;          // 0..3
#pragma unroll
        for (int i = 0; i < 16; ++i) {
            const unsigned int ci_l = c0 + i * 4;
            tile[ci_l][p_l] = f2bf(x[(ciBase + ci_l) * NPOS + pBase + p_l]);
        }
    }
    __syncthreads();
    {
        const unsigned int ci_l = t & 63;
        const unsigned int p0 = t >> 6;          // 0..3
#pragma unroll
        for (int i = 0; i < 16; ++i) {
            const unsigned int p_l = p0 + i * 4;
            const unsigned int p = pBase + p_l;
            const unsigned int hi = p / W;
            const unsigned int wi = p - hi * W;
            xp[((hi + 1) * HP + (wi + 1)) * CI + ciBase + ci_l] = tile[ci_l][p_l];
        }
    }
}

// ---- implicit GEMM: 128x128 block, 2 waves, wave-tile 128(M)x64(N), BK=32, dbuf ----
// Per iter per wave: 8 A-frags + 4 B-frags (12 ds_read_b128) -> 32 MFMA 16x16x32.
// Swizzle (4 chunks of 8 shorts per 32-short row):
//   store: lane l -> row +=(l>>2), slot l&3, source chunk (l&3)^((l>>2)&3)
//   read : chunk quad of row r lives at slot quad^(r&3); r&3 == ln15&3
__global__ __launch_bounds__(128, 2) void gemm_conv_kernel(
    const unsigned short* __restrict__ Ap,   // [256][2304] bf16
    const unsigned short* __restrict__ Xp,   // [226][226][256] bf16
    float* __restrict__ out)                 // [256][50176]
{
    __shared__ unsigned short Als[2][4096];  // 128 rows x 32
    __shared__ unsigned short Bls[2][4096];  // 128 rows x 32

    const int tid = threadIdx.x;
    const int Nb = blockIdx.x;               // 0..391
    const int Mb = blockIdx.y;               // 0..1
    const int wave = tid >> 6;               // 0..1
    const int lane = tid & 63;
    const int ln15 = lane & 15;
    const int quad = lane >> 4;
    const int sw = ln15 & 3;

    // ---- staging source pointers (each thread stages 4 A-chunks + 4 B-chunks) ----
    const int l2 = lane >> 2;                // 0..15
    const int c4 = (lane & 3) ^ (l2 & 3);    // swizzled source chunk

    const unsigned short* a_src[4];
    const unsigned short* b_src[4];
#pragma unroll
    for (int j = 0; j < 4; ++j) {
        const int row = (wave * 4 + j) * 16 + l2;          // 0..127
        a_src[j] = Ap + (Mb * 128 + row) * KDIM + c4 * 8;  // + kc*32
        unsigned int p = Nb * 128 + row;
        unsigned int hi = p / W, wi = p - hi * W;
        b_src[j] = Xp + (hi * HP + wi) * CI + c4 * 8;      // + tap/ci offset
    }

    f32x4 acc[8][4];
#pragma unroll
    for (int mi = 0; mi < 8; ++mi)
#pragma unroll
        for (int ni = 0; ni < 4; ++ni)
            acc[mi][ni] = (f32x4){0.f, 0.f, 0.f, 0.f};

    // stage tile kc into buffer buf (wave-uniform LDS base; lane*16B implicit)
    auto stage = [&](int kc, int buf) {
        const int tap = kc >> 3;             // 0..8
        const int dh = tap / 3, dw = tap - dh * 3;
        const int boff = (dh * HP + dw) * CI + (kc & 7) * 32;
        const int aoff = kc * 32;
#pragma unroll
        for (int j = 0; j < 4; ++j) {
            load_lds16(a_src[j] + aoff, &Als[buf][(wave * 4 + j) * 512]);
            load_lds16(b_src[j] + boff, &Bls[buf][(wave * 4 + j) * 512]);
        }
    };

    stage(0, 0);
    __syncthreads();                         // drain vmcnt: buffer 0 ready

    for (int kc = 0; kc < 72; ++kc) {
        const int cur = kc & 1;
        if (kc < 71) stage(kc + 1, cur ^ 1); // async into the OTHER buffer

        bf16x8 af[8], bfr[4];
#pragma unroll
        for (int mi = 0; mi < 8; ++mi)
            af[mi] = *(const bf16x8*)&Als[cur][(mi * 16 + ln15) * 32 + ((quad ^ sw) * 8)];
#pragma unroll
        for (int ni = 0; ni < 4; ++ni)
            bfr[ni] = *(const bf16x8*)&Bls[cur][(wave * 64 + ni * 16 + ln15) * 32 +
                                               ((quad ^ sw) * 8)];
#pragma unroll
        for (int mi = 0; mi < 8; ++mi)
#pragma unroll
            for (int ni = 0; ni < 4; ++ni)
                acc[mi][ni] = __builtin_amdgcn_mfma_f32_16x16x32_bf16(
                    af[mi], bfr[ni], acc[mi][ni], 0, 0, 0);

        __syncthreads();                     // joins: reads of cur done, next buffer landed
    }

    // epilogue: C/D layout col = lane&15 (n=p), row = quad*4 + reg (m=co)
    const int pcol = Nb * 128 + wave * 64 + ln15;
    const int corow = Mb * 128 + quad * 4;
#pragma unroll
    for (int mi = 0; mi < 8; ++mi)
#pragma unroll
        for (int ni = 0; ni < 4; ++ni)
#pragma unroll
            for (int r = 0; r < 4; ++r)
                out[(corow + mi * 16 + r) * NPOS + pcol + ni * 16] = acc[mi][ni][r];
}

extern "C" void kernel_launch(void* const* d_in, const int* in_sizes, int n_in,
                              void* d_out, int out_size, void* d_ws, size_t ws_size,
                              hipStream_t stream) {
    const float* x = (const float*)d_in[0];       // [1,256,224,224]
    const float* w = (const float*)d_in[1];       // [256,256,3,3]
    float* out = (float*)d_out;                   // [256,224,224]

    unsigned short* xp = (unsigned short*)d_ws;        // 13,075,456 shorts
    unsigned short* ap = xp + XP_ELEMS;                // 589,824 shorts

    prologue_kernel<<<AP_ELEMS / 256 + 900, 256, 0, stream>>>(w, ap, xp);
    xtrans_kernel<<<dim3(NPOS / 64, CI / 64), 256, 0, stream>>>(x, xp);
    gemm_conv_kernel<<<dim3(NPOS / 128, CO / 128), 128, 0, stream>>>(ap, xp, out);
}